// Round 2
// baseline (100.162 us; speedup 1.0000x reference)
//
#include <hip/hip_runtime.h>
#include <hip/hip_bf16.h>

static constexpr int NB  = 20;   // N
static constexpr int KK  = 8;    // K

// One thread handles TWO batch rows (grid-stride within block: tid and tid+256).
// Each block:
//  1) sniffs input dtypes (wave-uniform branches only),
//  2) computes the two softmaxes into LDS (tiny, redundant per block),
//  3) packs each row's 20 booleans into a bitmask and runs the (k,m) DP
//     entirely in registers (fully unrolled, S[21] in VGPRs).
__global__ __launch_bounds__(256) void pc_kernel(
    const void* __restrict__ xraw,
    const void* __restrict__ wleaf_raw,
    const void* __restrict__ w2_raw,
    void* __restrict__ outraw,
    int batch)
{
    __shared__ float s_wsm[(NB + 1) * NB];          // 21*20 leaf softmax
    __shared__ float s_w20[(KK + 1) * (NB + 1)];    // w2[...,0]
    __shared__ float s_w21[(KK + 1) * (NB + 1)];    // w2[...,1]
    __shared__ int s_flagX;  // 0=int32, 1=uint8, 2=bf16
    __shared__ int s_flagW;  // 0=f32, 1=bf16
    __shared__ int s_cntW;
    __shared__ int s_xKind;

    const int tid = threadIdx.x;

    if (tid == 0) { s_cntW = 0; s_xKind = 0; }
    __syncthreads();

    // ---- dtype detection (reads safe under the smallest interpretation) ----
    if (tid < 64) {
        unsigned v = ((const unsigned*)xraw)[tid];
        if (v > 1u) {
            if (((v & 0xFFFFu) == 0x3F80u) || ((v >> 16) == 0x3F80u))
                atomicOr(&s_xKind, 2);
            else
                atomicOr(&s_xKind, 1);
        }
    } else if (tid < 64 + 192) {
        unsigned v = ((const unsigned*)wleaf_raw)[tid - 64];
        unsigned hb = (v >> 8) & 0xFFu;
        if (hb >= 0x30u && hb <= 0x40u) atomicAdd(&s_cntW, 1);
    }
    __syncthreads();
    if (tid == 0) {
        int xk = s_xKind;
        s_flagX = (xk & 2) ? 2 : ((xk & 1) ? 1 : 0);
        s_flagW = (s_cntW > 96) ? 1 : 0;
    }
    __syncthreads();
    const int fX = s_flagX;
    const int fW = s_flagW;

    auto WL = [&](int idx) -> float {
        return fW ? __bfloat162float(((const __hip_bfloat16*)wleaf_raw)[idx])
                  : ((const float*)wleaf_raw)[idx];
    };
    auto W2v = [&](int idx) -> float {
        return fW ? __bfloat162float(((const __hip_bfloat16*)w2_raw)[idx])
                  : ((const float*)w2_raw)[idx];
    };

    // ---- leaf softmax rows m = 1..20 (thread m handles row m serially) ----
    if (tid >= 1 && tid <= NB) {
        const int m = tid;
        float mx = -1e30f;
        for (int i = 0; i < m; ++i) mx = fmaxf(mx, WL(m * NB + i));
        float s = 0.f;
        for (int i = 0; i < m; ++i) s += expf(WL(m * NB + i) - mx);
        const float inv = 1.f / s;
        for (int i = 0; i < m; ++i) s_wsm[m * NB + i] = expf(WL(m * NB + i) - mx) * inv;
    }
    // ---- w2 pair softmax, 9*21 = 189 pairs on threads 21..209 ----
    if (tid >= 21 && tid < 21 + (KK + 1) * (NB + 1)) {
        const int idx = tid - 21;
        const float a = W2v(idx * 2 + 0);
        const float b = W2v(idx * 2 + 1);
        const float mx = fmaxf(a, b);
        const float ea = expf(a - mx), eb = expf(b - mx);
        const float inv = 1.f / (ea + eb);
        s_w20[idx] = ea * inv;
        s_w21[idx] = eb * inv;
    }
    __syncthreads();

    // ---- pack a row's 20 booleans into a bitmask ----
    auto packRow = [&](int b) -> unsigned {
        unsigned bits = 0;
        if (fX == 0) {
            const int4* row = (const int4*)((const int*)xraw + (size_t)b * NB);
            #pragma unroll
            for (int j = 0; j < 5; ++j) {
                int4 v = row[j];
                bits |= (unsigned)(v.x != 0) << (4 * j + 0);
                bits |= (unsigned)(v.y != 0) << (4 * j + 1);
                bits |= (unsigned)(v.z != 0) << (4 * j + 2);
                bits |= (unsigned)(v.w != 0) << (4 * j + 3);
            }
        } else if (fX == 1) {
            const unsigned* p = (const unsigned*)((const unsigned char*)xraw + (size_t)b * NB);
            #pragma unroll
            for (int j = 0; j < 5; ++j) {
                unsigned v = p[j];
                bits |= (unsigned)(((v      ) & 0xFFu) != 0) << (4 * j + 0);
                bits |= (unsigned)(((v >>  8) & 0xFFu) != 0) << (4 * j + 1);
                bits |= (unsigned)(((v >> 16) & 0xFFu) != 0) << (4 * j + 2);
                bits |= (unsigned)(((v >> 24)       ) != 0) << (4 * j + 3);
            }
        } else {
            const unsigned* p = (const unsigned*)((const unsigned short*)xraw + (size_t)b * NB);
            #pragma unroll
            for (int j = 0; j < 10; ++j) {
                unsigned v = p[j];
                bits |= (unsigned)((v & 0xFFFFu) != 0) << (2 * j + 0);
                bits |= (unsigned)((v >> 16)     != 0) << (2 * j + 1);
            }
        }
        return bits;
    };

    // ---- full DP for one row's bitmask ----
    auto runDP = [&](unsigned bits) -> float {
        float S[NB + 1];
        S[0] = 0.f;
        int pc = 0;
        int onlyIdx = 0;
        #pragma unroll
        for (int m = 1; m <= NB; ++m) {
            if ((bits >> (m - 1)) & 1u) { pc++; onlyIdx = m - 1; }
            const float wv = s_wsm[m * NB + onlyIdx];  // valid: onlyIdx < m
            S[m] = (pc == 1) ? wv : 0.f;
        }
        #pragma unroll
        for (int k = 2; k <= KK; ++k) {
            const unsigned lm = (1u << k) - 1u;
            float prevNew = ((bits & lm) == lm) ? 1.f : 0.f;  // pre[:, k-1]
            float oldPrev = S[k];
            S[k] = prevNew;
            #pragma unroll
            for (int m = k + 1; m <= NB; ++m) {
                const float oldCur = S[m];
                const float t = ((bits >> (m - 1)) & 1u) ? oldPrev : 0.f;
                const float cur = fmaf(s_w20[k * (NB + 1) + m], prevNew,
                                       s_w21[k * (NB + 1) + m] * t);
                S[m] = cur;
                prevNew = cur;
                oldPrev = oldCur;
            }
        }
        return S[NB];
    };

    const int b0 = blockIdx.x * 512 + tid;
    const int b1 = b0 + 256;

    if (b0 < batch) {
        const unsigned bits0 = packRow(b0);
        const unsigned bits1 = (b1 < batch) ? packRow(b1) : 0u;
        const float r0 = runDP(bits0);
        if (fW) ((__hip_bfloat16*)outraw)[b0] = __float2bfloat16(r0);
        else    ((float*)outraw)[b0]          = r0;
        if (b1 < batch) {
            const float r1 = runDP(bits1);
            if (fW) ((__hip_bfloat16*)outraw)[b1] = __float2bfloat16(r1);
            else    ((float*)outraw)[b1]          = r1;
        }
    }
}

extern "C" void kernel_launch(void* const* d_in, const int* in_sizes, int n_in,
                              void* d_out, int out_size, void* d_ws, size_t ws_size,
                              hipStream_t stream) {
    (void)n_in; (void)d_ws; (void)ws_size;
    const int batch = in_sizes[0] / NB;            // 524288
    const int blocks = (batch + 511) / 512;        // 1024 (2 rows/thread)
    pc_kernel<<<blocks, 256, 0, stream>>>(d_in[0], d_in[1], d_in[2], d_out, batch);
}

// Round 3
// 91.098 us; speedup vs baseline: 1.0995x; 1.0995x over previous
//
#include <hip/hip_runtime.h>
#include <hip/hip_bf16.h>

static constexpr int NB  = 20;   // N
static constexpr int KK  = 8;    // K

// One thread per batch element (round-1 config: best measured).
// Each block:
//  1) sniffs input dtypes (wave-uniform branches only),
//  2) computes the two softmaxes into LDS (tiny, redundant per block),
//  3) packs this thread's 20 booleans into a bitmask and runs the (k,m) DP
//     entirely in registers (fully unrolled, S[21] in VGPRs).
__global__ __launch_bounds__(256) void pc_kernel(
    const void* __restrict__ xraw,
    const void* __restrict__ wleaf_raw,
    const void* __restrict__ w2_raw,
    void* __restrict__ outraw,
    int batch)
{
    __shared__ float s_wsm[(NB + 1) * NB];          // 21*20 leaf softmax
    __shared__ float s_w20[(KK + 1) * (NB + 1)];    // w2[...,0]
    __shared__ float s_w21[(KK + 1) * (NB + 1)];    // w2[...,1]
    __shared__ int s_flagX;  // 0=int32, 1=uint8, 2=bf16
    __shared__ int s_flagW;  // 0=f32, 1=bf16
    __shared__ int s_cntW;
    __shared__ int s_xKind;

    const int tid = threadIdx.x;

    if (tid == 0) { s_cntW = 0; s_xKind = 0; }
    __syncthreads();

    // ---- dtype detection (reads safe under the smallest interpretation) ----
    if (tid < 64) {
        unsigned v = ((const unsigned*)xraw)[tid];
        if (v > 1u) {
            if (((v & 0xFFFFu) == 0x3F80u) || ((v >> 16) == 0x3F80u))
                atomicOr(&s_xKind, 2);
            else
                atomicOr(&s_xKind, 1);
        }
    } else if (tid < 64 + 192) {
        unsigned v = ((const unsigned*)wleaf_raw)[tid - 64];
        unsigned hb = (v >> 8) & 0xFFu;
        if (hb >= 0x30u && hb <= 0x40u) atomicAdd(&s_cntW, 1);
    }
    __syncthreads();
    if (tid == 0) {
        int xk = s_xKind;
        s_flagX = (xk & 2) ? 2 : ((xk & 1) ? 1 : 0);
        s_flagW = (s_cntW > 96) ? 1 : 0;
    }
    __syncthreads();
    const int fX = s_flagX;
    const int fW = s_flagW;

    auto WL = [&](int idx) -> float {
        return fW ? __bfloat162float(((const __hip_bfloat16*)wleaf_raw)[idx])
                  : ((const float*)wleaf_raw)[idx];
    };
    auto W2v = [&](int idx) -> float {
        return fW ? __bfloat162float(((const __hip_bfloat16*)w2_raw)[idx])
                  : ((const float*)w2_raw)[idx];
    };

    // ---- leaf softmax rows m = 1..20 (thread m handles row m serially) ----
    if (tid >= 1 && tid <= NB) {
        const int m = tid;
        float mx = -1e30f;
        for (int i = 0; i < m; ++i) mx = fmaxf(mx, WL(m * NB + i));
        float s = 0.f;
        for (int i = 0; i < m; ++i) s += expf(WL(m * NB + i) - mx);
        const float inv = 1.f / s;
        for (int i = 0; i < m; ++i) s_wsm[m * NB + i] = expf(WL(m * NB + i) - mx) * inv;
    }
    // ---- w2 pair softmax, 9*21 = 189 pairs on threads 21..209 ----
    if (tid >= 21 && tid < 21 + (KK + 1) * (NB + 1)) {
        const int idx = tid - 21;
        const float a = W2v(idx * 2 + 0);
        const float b = W2v(idx * 2 + 1);
        const float mx = fmaxf(a, b);
        const float ea = expf(a - mx), eb = expf(b - mx);
        const float inv = 1.f / (ea + eb);
        s_w20[idx] = ea * inv;
        s_w21[idx] = eb * inv;
    }
    __syncthreads();

    const int b = blockIdx.x * 256 + tid;
    if (b >= batch) return;

    // ---- pack this row's 20 booleans into a bitmask ----
    unsigned bits = 0;
    if (fX == 0) {
        // int32 bools: row stride 80 B, 16B-aligned -> 5x int4
        const int4* row = (const int4*)((const int*)xraw + (size_t)b * NB);
        #pragma unroll
        for (int j = 0; j < 5; ++j) {
            int4 v = row[j];
            bits |= (unsigned)(v.x != 0) << (4 * j + 0);
            bits |= (unsigned)(v.y != 0) << (4 * j + 1);
            bits |= (unsigned)(v.z != 0) << (4 * j + 2);
            bits |= (unsigned)(v.w != 0) << (4 * j + 3);
        }
    } else if (fX == 1) {
        // byte bools: row stride 20 B, 4B-aligned -> 5 dwords
        const unsigned* p = (const unsigned*)((const unsigned char*)xraw + (size_t)b * NB);
        #pragma unroll
        for (int j = 0; j < 5; ++j) {
            unsigned v = p[j];
            bits |= (unsigned)(((v      ) & 0xFFu) != 0) << (4 * j + 0);
            bits |= (unsigned)(((v >>  8) & 0xFFu) != 0) << (4 * j + 1);
            bits |= (unsigned)(((v >> 16) & 0xFFu) != 0) << (4 * j + 2);
            bits |= (unsigned)(((v >> 24)       ) != 0) << (4 * j + 3);
        }
    } else {
        // bf16 bools: row stride 40 B -> 10 dwords of half pairs
        const unsigned* p = (const unsigned*)((const unsigned short*)xraw + (size_t)b * NB);
        #pragma unroll
        for (int j = 0; j < 10; ++j) {
            unsigned v = p[j];
            bits |= (unsigned)((v & 0xFFFFu) != 0) << (2 * j + 0);
            bits |= (unsigned)((v >> 16)     != 0) << (2 * j + 1);
        }
    }

    // ---- k = 1 row: S1[m] = [popcount(bits & (2^m-1)) == 1] * wsm[m][the bit] ----
    float S[NB + 1];
    S[0] = 0.f;
    int pc = 0;
    int onlyIdx = 0;
    #pragma unroll
    for (int m = 1; m <= NB; ++m) {
        if ((bits >> (m - 1)) & 1u) { pc++; onlyIdx = m - 1; }
        const float wv = s_wsm[m * NB + onlyIdx];  // valid: onlyIdx < m
        S[m] = (pc == 1) ? wv : 0.f;
    }

    // ---- k = 2..K: row[m] = w0*row[m-1] + w1*S_prev[m-1]*x[m-1], in place ----
    #pragma unroll
    for (int k = 2; k <= KK; ++k) {
        const unsigned lm = (1u << k) - 1u;
        float prevNew = ((bits & lm) == lm) ? 1.f : 0.f;  // pre[:, k-1]
        float oldPrev = S[k];                              // S_prev[m-1] for m=k+1
        S[k] = prevNew;
        #pragma unroll
        for (int m = k + 1; m <= NB; ++m) {
            const float oldCur = S[m];
            const float t = ((bits >> (m - 1)) & 1u) ? oldPrev : 0.f;
            const float cur = fmaf(s_w20[k * (NB + 1) + m], prevNew,
                                   s_w21[k * (NB + 1) + m] * t);
            S[m] = cur;
            prevNew = cur;
            oldPrev = oldCur;
        }
    }

    if (fW) ((__hip_bfloat16*)outraw)[b] = __float2bfloat16(S[NB]);
    else    ((float*)outraw)[b]          = S[NB];
}

extern "C" void kernel_launch(void* const* d_in, const int* in_sizes, int n_in,
                              void* d_out, int out_size, void* d_ws, size_t ws_size,
                              hipStream_t stream) {
    (void)n_in; (void)d_ws; (void)ws_size;
    const int batch = in_sizes[0] / NB;           // 524288
    const int blocks = (batch + 255) / 256;       // 2048
    pc_kernel<<<blocks, 256, 0, stream>>>(d_in[0], d_in[1], d_in[2], d_out, batch);
}